// Round 20
// baseline (200.368 us; speedup 1.0000x reference)
//
#include <hip/hip_runtime.h>
#include <math.h>

#define N_NODES 50000
#define N_EDGES 800000
#define F_IN 128
#define HIDDEN 256
#define N_CLASSES 40

#define CHUNK 256
#define NCHUNK ((N_NODES + CHUNK - 1) / CHUNK)  // 196
#define IDXCAP 1024
#define NB 32                                    // nodes per block (layer1)
#define NBLK ((N_NODES + NB - 1) / NB)           // 1563
#define NB2K 64                                  // nodes per block (k2b)
#define NBLK2 ((N_NODES + NB2K - 1) / NB2K)      // 782
#define IDXCAP2 1536

typedef __attribute__((ext_vector_type(8))) short bf16x8;
typedef __attribute__((ext_vector_type(4))) float f32x4;
typedef __attribute__((ext_vector_type(2))) float f32x2;
typedef __attribute__((ext_vector_type(8))) unsigned short u16x8;

// ---------------- bf16 helpers ----------------

__device__ __forceinline__ float bf2f(unsigned short u) {
    unsigned int t = ((unsigned int)u) << 16;
    float f;
    __builtin_memcpy(&f, &t, 4);
    return f;
}

__device__ __forceinline__ unsigned short f2bf(float f) {
    unsigned int t;
    __builtin_memcpy(&t, &f, 4);
    unsigned int r = (t + 0x7fffu + ((t >> 16) & 1u)) >> 16;  // RNE
    return (unsigned short)r;
}

// ---------------- fp8 e4m3 (OCP) helpers ----------------

__device__ __forceinline__ unsigned char f2fp8(float f) {
    unsigned int bits = __float_as_uint(f);
    unsigned int sign = (bits >> 24) & 0x80u;
    float af = fabsf(f);
    if (af >= 448.f) return (unsigned char)(sign | 0x7Eu);
    if (af < 0.015625f) {
        int m = __float2int_rn(af * 512.f);
        return (unsigned char)(sign | (unsigned int)m);
    }
    unsigned int u = bits & 0x7FFFFFFFu;
    u += 0x7FFFFu + ((u >> 20) & 1u);
    unsigned int e = (u >> 23) - 120u;
    unsigned int m = (u >> 20) & 7u;
    return (unsigned char)(sign | (e << 3) | m);
}

__device__ __forceinline__ void addfp8x8(unsigned int wx, unsigned int wy, float* a) {
#if __has_builtin(__builtin_amdgcn_cvt_pk_f32_fp8)
    f32x2 p;
    p = __builtin_amdgcn_cvt_pk_f32_fp8(wx, false); a[0] += p.x; a[1] += p.y;
    p = __builtin_amdgcn_cvt_pk_f32_fp8(wx, true);  a[2] += p.x; a[3] += p.y;
    p = __builtin_amdgcn_cvt_pk_f32_fp8(wy, false); a[4] += p.x; a[5] += p.y;
    p = __builtin_amdgcn_cvt_pk_f32_fp8(wy, true);  a[6] += p.x; a[7] += p.y;
#else
    unsigned int ww[2] = {wx, wy};
#pragma unroll
    for (int h = 0; h < 2; ++h) {
        unsigned int tlo = ww[h] & 0x00ff00ffu;
        unsigned int thi = (ww[h] >> 8) & 0x00ff00ffu;
        unsigned int rlo = ((tlo & 0x00800080u) << 8) + ((tlo & 0x007f007fu) << 4) + 0x3C003C00u;
        unsigned int rhi = ((thi & 0x00800080u) << 8) + ((thi & 0x007f007fu) << 4) + 0x3C003C00u;
        a[h * 4 + 0] += __uint_as_float(rlo << 16);
        a[h * 4 + 1] += __uint_as_float(rhi << 16);
        a[h * 4 + 2] += __uint_as_float(rlo & 0xffff0000u);
        a[h * 4 + 3] += __uint_as_float(rhi & 0xffff0000u);
    }
#endif
}

__device__ __forceinline__ void addfp8x16(uint4 w, float* a) {
    addfp8x8(w.x, w.y, a);
    addfp8x8(w.z, w.w, a + 8);
}

// ---------------- CSR build ----------------

__global__ void zero_counts(int* __restrict__ counts) {
    int i = blockIdx.x * blockDim.x + threadIdx.x;
    if (i < N_NODES) counts[i] = 0;
}

__global__ void count_kernel(const int* __restrict__ dst, int* __restrict__ counts) {
    int e = blockIdx.x * blockDim.x + threadIdx.x;
    if (e < N_EDGES) {
        int d = dst[e];
        d = (d < 0) ? 0 : (d >= N_NODES ? N_NODES - 1 : d);
        atomicAdd(&counts[d], 1);
    }
}

__global__ __launch_bounds__(256) void scan_partials(const int* __restrict__ counts,
                                                     int* __restrict__ bsum) {
    __shared__ int red[4];
    int b = blockIdx.x;
    int i = b * CHUNK + threadIdx.x;
    int v = (i < N_NODES) ? counts[i] : 0;
    for (int off = 32; off > 0; off >>= 1) v += __shfl_down(v, off, 64);
    int wave = threadIdx.x >> 6;
    int lane = threadIdx.x & 63;
    if (lane == 0) red[wave] = v;
    __syncthreads();
    if (threadIdx.x == 0) bsum[b] = red[0] + red[1] + red[2] + red[3];
}

__global__ __launch_bounds__(256) void scan_apply2(const int* __restrict__ counts,
                                                   const int* __restrict__ bsum,
                                                   int* __restrict__ row_off,
                                                   int* __restrict__ cursor,
                                                   float* __restrict__ inv_deg) {
    __shared__ int s[256];
    __shared__ int red[4];
    int b = blockIdx.x;
    int tid = threadIdx.x;
    int r = (tid < b && tid < NCHUNK) ? bsum[tid] : 0;
    for (int off = 32; off > 0; off >>= 1) r += __shfl_down(r, off, 64);
    if ((tid & 63) == 0) red[tid >> 6] = r;
    int i = b * CHUNK + tid;
    int v = (i < N_NODES) ? counts[i] : 0;
    s[tid] = v;
    __syncthreads();
    int boff_b = red[0] + red[1] + red[2] + red[3];
    for (int off = 1; off < 256; off <<= 1) {
        int t = (tid >= off) ? s[tid - off] : 0;
        __syncthreads();
        s[tid] += t;
        __syncthreads();
    }
    if (i < N_NODES) {
        int excl = boff_b + s[tid] - v;
        row_off[i] = excl;
        cursor[i] = excl;
        inv_deg[i] = 1.0f / fmaxf((float)v, 1.0f);
        if (i == N_NODES - 1) row_off[N_NODES] = excl + v;
    }
}

__global__ void fill_kernel(const int* __restrict__ ei, int* __restrict__ cursor,
                            int* __restrict__ csr_src) {
    int e = blockIdx.x * blockDim.x + threadIdx.x;
    if (e < N_EDGES) {
        int s = ei[e];
        int d = ei[N_EDGES + e];
        s = (s < 0) ? 0 : (s >= N_NODES ? N_NODES - 1 : s);
        d = (d < 0) ? 0 : (d >= N_NODES ? N_NODES - 1 : d);
        int pos = atomicAdd(&cursor[d], 1);
        if (pos >= 0 && pos < N_EDGES) csr_src[pos] = s;
    }
}

// ---------------- x -> bf16 + fp8 conversion ----------------

__global__ void conv_x(const float* __restrict__ x, unsigned short* __restrict__ x16,
                       unsigned char* __restrict__ x8) {
    int i = blockIdx.x * blockDim.x + threadIdx.x;
    if (i < N_NODES * F_IN / 4) {
        float4 v = reinterpret_cast<const float4*>(x)[i];
        ushort4 o;
        o.x = f2bf(v.x); o.y = f2bf(v.y); o.z = f2bf(v.z); o.w = f2bf(v.w);
        reinterpret_cast<ushort4*>(x16)[i] = o;
        uchar4 c;
        c.x = f2fp8(v.x); c.y = f2fp8(v.y); c.z = f2fp8(v.z); c.w = f2fp8(v.w);
        reinterpret_cast<uchar4*>(x8)[i] = c;
    }
}

// ---------------- weight packs ----------------

__global__ void pack_w1(const float* __restrict__ W1l, const float* __restrict__ W1r,
                        unsigned short* __restrict__ Wpk) {
    int n = blockIdx.x;
    int k = threadIdx.x;
    float v = (k < F_IN) ? W1l[(size_t)k * HIDDEN + n] : W1r[(size_t)(k - F_IN) * HIDDEN + n];
    Wpk[(size_t)n * 256 + k] = f2bf(v);
}

__global__ void pack_w2n(const float* __restrict__ W2l, const float* __restrict__ W2r,
                         unsigned short* __restrict__ Wpk2n) {
    int n = blockIdx.x;   // 0..127
    int k = threadIdx.x;  // 0..255
    float v = 0.f;
    if (n < 64) {
        if (n < N_CLASSES) v = W2l[(size_t)k * N_CLASSES + n];
    } else {
        int m = n - 64;
        if (m < N_CLASSES) v = W2r[(size_t)k * N_CLASSES + m];
    }
    Wpk2n[(size_t)n * 256 + k] = f2bf(v);
}

// ---------------- layer1_fused: 8-lane-group fp8 gather + MFMA1+relu + proj2 ----------
// 256 threads, 32 nodes/block; 8 rows per wave-load instruction. Phase 4 now emits
// fp8 hWl padded to 64 cols (pad = fp8 zero) for k2b's 16-rows/inst gather.

#define AS1_STRIDE 264

__global__ __launch_bounds__(256) void layer1_fused(
    const unsigned short* __restrict__ x16, const unsigned char* __restrict__ x8,
    const int* __restrict__ row_off, const int* __restrict__ csr_src,
    const float* __restrict__ inv_deg, const unsigned short* __restrict__ Wpk,
    const float* __restrict__ b1, const unsigned short* __restrict__ Wpk2n,
    const float* __restrict__ b2, unsigned char* __restrict__ hWl8,
    unsigned short* __restrict__ hWr) {
    __shared__ __align__(16) unsigned short As[NB][AS1_STRIDE];  // A-tile, then H-tile
    __shared__ int eidx[IDXCAP];
    __shared__ int s_roff[NB + 1];
    int n0 = blockIdx.x * NB;
    int tid = threadIdx.x;
    int wave = tid >> 6;
    int lane = tid & 63;

    if (tid < NB + 1) {
        int idx = n0 + tid;
        s_roff[tid] = row_off[idx > N_NODES ? N_NODES : idx];
    }
    __syncthreads();
    int eb0 = s_roff[0];
    int eb1 = s_roff[NB];
    int cnt = eb1 - eb0;
    int staged = cnt < IDXCAP ? cnt : IDXCAP;
    for (int t = tid; t < staged; t += 256) eidx[t] = csr_src[eb0 + t];
    __syncthreads();

    // ---- phase 1: gather, 8-lane group per node ----
    int g = tid >> 3;   // node 0..31
    int gl = tid & 7;   // 16 fp8 features at gl*16
    {
        int n = n0 + g;
        int e0 = s_roff[g], e1 = s_roff[g + 1];
        int deg = e1 - e0;
        const int* ip;
        int ib;
        if (e1 - eb0 <= staged) { ip = eidx; ib = e0 - eb0; }
        else                    { ip = csr_src; ib = e0; }
        u16x8 self0 = {0, 0, 0, 0, 0, 0, 0, 0}, self1 = {0, 0, 0, 0, 0, 0, 0, 0};
        if (n < N_NODES) {
            self0 = *reinterpret_cast<const u16x8*>(x16 + (size_t)n * F_IN + gl * 16);
            self1 = *reinterpret_cast<const u16x8*>(x16 + (size_t)n * F_IN + gl * 16 + 8);
        }
        float a[16];
#pragma unroll
        for (int i = 0; i < 16; ++i) a[i] = 0.f;
        int it = 0;
        for (; it + 7 < deg; it += 8) {
            int ss[8];
#pragma unroll
            for (int u = 0; u < 8; ++u) ss[u] = ip[ib + it + u];
            uint4 vv[8];
#pragma unroll
            for (int u = 0; u < 8; ++u)
                vv[u] = *reinterpret_cast<const uint4*>(x8 + (size_t)ss[u] * F_IN + gl * 16);
#pragma unroll
            for (int u = 0; u < 8; ++u) addfp8x16(vv[u], a);
        }
        if (it + 3 < deg) {
            int ss[4];
#pragma unroll
            for (int u = 0; u < 4; ++u) ss[u] = ip[ib + it + u];
            uint4 vv[4];
#pragma unroll
            for (int u = 0; u < 4; ++u)
                vv[u] = *reinterpret_cast<const uint4*>(x8 + (size_t)ss[u] * F_IN + gl * 16);
#pragma unroll
            for (int u = 0; u < 4; ++u) addfp8x16(vv[u], a);
            it += 4;
        }
        for (; it < deg; ++it) {
            uint4 v = *reinterpret_cast<const uint4*>(x8 + (size_t)ip[ib + it] * F_IN + gl * 16);
            addfp8x16(v, a);
        }
        float id = (n < N_NODES) ? inv_deg[n] : 0.f;
        u16x8 m0, m1;
#pragma unroll
        for (int i = 0; i < 8; ++i) { m0[i] = f2bf(a[i] * id); m1[i] = f2bf(a[8 + i] * id); }
        *reinterpret_cast<u16x8*>(&As[g][gl * 16]) = m0;
        *reinterpret_cast<u16x8*>(&As[g][gl * 16 + 8]) = m1;
        *reinterpret_cast<u16x8*>(&As[g][F_IN + gl * 16]) = self0;
        *reinterpret_cast<u16x8*>(&As[g][F_IN + gl * 16 + 8]) = self1;
    }
    __syncthreads();

    // ---- phase 2: MFMA [mean|x]@Wpk1, 2 row-blocks (m89-verified layout) ----
    int mrow = lane & 15;
    int kg = lane >> 4;
    f32x4 acc00 = {0,0,0,0}, acc01 = {0,0,0,0}, acc02 = {0,0,0,0}, acc03 = {0,0,0,0};
    f32x4 acc10 = {0,0,0,0}, acc11 = {0,0,0,0}, acc12 = {0,0,0,0}, acc13 = {0,0,0,0};
    const unsigned short* wp = Wpk + ((size_t)(wave * 4) * 16 + mrow) * 256 + kg * 8;
#pragma unroll
    for (int ks = 0; ks < 8; ++ks) {
        bf16x8 a0 = *reinterpret_cast<const bf16x8*>(&As[mrow][ks * 32 + kg * 8]);
        bf16x8 a1 = *reinterpret_cast<const bf16x8*>(&As[16 + mrow][ks * 32 + kg * 8]);
        bf16x8 b0 = *reinterpret_cast<const bf16x8*>(wp + 0 * 16 * 256 + ks * 32);
        bf16x8 b1f = *reinterpret_cast<const bf16x8*>(wp + 1 * 16 * 256 + ks * 32);
        bf16x8 b2f = *reinterpret_cast<const bf16x8*>(wp + 2 * 16 * 256 + ks * 32);
        bf16x8 b3f = *reinterpret_cast<const bf16x8*>(wp + 3 * 16 * 256 + ks * 32);
        acc00 = __builtin_amdgcn_mfma_f32_16x16x32_bf16(a0, b0, acc00, 0, 0, 0);
        acc01 = __builtin_amdgcn_mfma_f32_16x16x32_bf16(a0, b1f, acc01, 0, 0, 0);
        acc02 = __builtin_amdgcn_mfma_f32_16x16x32_bf16(a0, b2f, acc02, 0, 0, 0);
        acc03 = __builtin_amdgcn_mfma_f32_16x16x32_bf16(a0, b3f, acc03, 0, 0, 0);
        acc10 = __builtin_amdgcn_mfma_f32_16x16x32_bf16(a1, b0, acc10, 0, 0, 0);
        acc11 = __builtin_amdgcn_mfma_f32_16x16x32_bf16(a1, b1f, acc11, 0, 0, 0);
        acc12 = __builtin_amdgcn_mfma_f32_16x16x32_bf16(a1, b2f, acc12, 0, 0, 0);
        acc13 = __builtin_amdgcn_mfma_f32_16x16x32_bf16(a1, b3f, acc13, 0, 0, 0);
    }
    __syncthreads();  // all As reads done; buffer becomes H

    // ---- phase 3: h = relu(acc + b1) -> same LDS buffer ----
    {
        f32x4 r0[4] = {acc00, acc01, acc02, acc03};
        f32x4 r1[4] = {acc10, acc11, acc12, acc13};
#pragma unroll
        for (int i = 0; i < 4; ++i) {
            int n = (wave * 4 + i) * 16 + mrow;
            float bb = b1[n];
#pragma unroll
            for (int r = 0; r < 4; ++r) {
                int row = kg * 4 + r;
                As[row][n] = f2bf(fmaxf(r0[i][r] + bb, 0.f));
                As[16 + row][n] = f2bf(fmaxf(r1[i][r] + bb, 0.f));
            }
        }
    }
    __syncthreads();

    // ---- phase 4: proj2 -- hWl8 = fp8(h@W2l) [n][64] (pad 0), hWr = h@W2r + b2 ----
    f32x4 accL0 = {0,0,0,0}, accR0 = {0,0,0,0}, accL1 = {0,0,0,0}, accR1 = {0,0,0,0};
    const unsigned short* wpL = Wpk2n + ((size_t)(wave * 16 + mrow)) * 256 + kg * 8;
    const unsigned short* wpR = Wpk2n + ((size_t)((wave + 4) * 16 + mrow)) * 256 + kg * 8;
#pragma unroll
    for (int ks = 0; ks < 8; ++ks) {
        bf16x8 a0 = *reinterpret_cast<const bf16x8*>(&As[mrow][ks * 32 + kg * 8]);
        bf16x8 a1 = *reinterpret_cast<const bf16x8*>(&As[16 + mrow][ks * 32 + kg * 8]);
        bf16x8 bL = *reinterpret_cast<const bf16x8*>(wpL + ks * 32);
        bf16x8 bR = *reinterpret_cast<const bf16x8*>(wpR + ks * 32);
        accL0 = __builtin_amdgcn_mfma_f32_16x16x32_bf16(a0, bL, accL0, 0, 0, 0);
        accR0 = __builtin_amdgcn_mfma_f32_16x16x32_bf16(a0, bR, accR0, 0, 0, 0);
        accL1 = __builtin_amdgcn_mfma_f32_16x16x32_bf16(a1, bL, accL1, 0, 0, 0);
        accR1 = __builtin_amdgcn_mfma_f32_16x16x32_bf16(a1, bR, accR1, 0, 0, 0);
    }
    int col = wave * 16 + mrow;  // 0..63
    bool cv = (col < N_CLASSES);
    float bb2 = cv ? b2[col] : 0.f;
#pragma unroll
    for (int r = 0; r < 4; ++r) {
        int row0 = n0 + kg * 4 + r;
        int row1 = row0 + 16;
        if (row0 < N_NODES) {
            hWl8[(size_t)row0 * 64 + col] = f2fp8(cv ? accL0[r] : 0.f);
            if (cv) hWr[(size_t)row0 * N_CLASSES + col] = f2bf(accR0[r] + bb2);
        }
        if (row1 < N_NODES) {
            hWl8[(size_t)row1 * 64 + col] = f2fp8(cv ? accL1[r] : 0.f);
            if (cv) hWr[(size_t)row1 * N_CLASSES + col] = f2bf(accR1[r] + bb2);
        }
    }
}

// ---------------- k2b: 4-lane-group fp8 gather of hWl8 (64-B rows) + log_softmax ----------
// Group = 4 lanes x uint4 (16B) = one 64-B row => 16 rows per wave-load instruction.
// 64 nodes/block, 256 threads. Lane gl owns classes gl*16..gl*16+15 (nv valid).

__global__ __launch_bounds__(256) void k2b(
    const unsigned char* __restrict__ hWl8, const unsigned short* __restrict__ hWr,
    const int* __restrict__ row_off, const int* __restrict__ csr_src,
    const float* __restrict__ inv_deg, float* __restrict__ out) {
    __shared__ int eidx[IDXCAP2];
    __shared__ int s_roff[NB2K + 1];
    int n0 = blockIdx.x * NB2K;
    int tid = threadIdx.x;

    if (tid < NB2K + 1) {
        int idx = n0 + tid;
        s_roff[tid] = row_off[idx > N_NODES ? N_NODES : idx];
    }
    __syncthreads();
    int eb0 = s_roff[0];
    int eb1 = s_roff[NB2K];
    int cnt = eb1 - eb0;
    int staged = cnt < IDXCAP2 ? cnt : IDXCAP2;
    for (int t = tid; t < staged; t += 256) eidx[t] = csr_src[eb0 + t];
    __syncthreads();

    int g = tid >> 2;   // node 0..63
    int gl = tid & 3;   // classes gl*16 .. gl*16+15
    int nv = N_CLASSES - gl * 16;
    nv = nv < 0 ? 0 : (nv > 16 ? 16 : nv);  // 16,16,8,0

    int n = n0 + g;
    int e0 = s_roff[g], e1 = s_roff[g + 1];
    int deg = e1 - e0;
    const int* ip;
    int ib;
    if (e1 - eb0 <= staged) { ip = eidx; ib = e0 - eb0; }
    else                    { ip = csr_src; ib = e0; }

    float a[16];
#pragma unroll
    for (int i = 0; i < 16; ++i) a[i] = 0.f;

    int it = 0;
    for (; it + 7 < deg; it += 8) {  // 8 rows in flight per group
        int ss[8];
#pragma unroll
        for (int u = 0; u < 8; ++u) ss[u] = ip[ib + it + u];
        uint4 vv[8];
#pragma unroll
        for (int u = 0; u < 8; ++u)
            vv[u] = *reinterpret_cast<const uint4*>(hWl8 + (size_t)ss[u] * 64 + gl * 16);
#pragma unroll
        for (int u = 0; u < 8; ++u) addfp8x16(vv[u], a);
    }
    if (it + 3 < deg) {
        int ss[4];
#pragma unroll
        for (int u = 0; u < 4; ++u) ss[u] = ip[ib + it + u];
        uint4 vv[4];
#pragma unroll
        for (int u = 0; u < 4; ++u)
            vv[u] = *reinterpret_cast<const uint4*>(hWl8 + (size_t)ss[u] * 64 + gl * 16);
#pragma unroll
        for (int u = 0; u < 4; ++u) addfp8x16(vv[u], a);
        it += 4;
    }
    for (; it < deg; ++it) {
        uint4 v = *reinterpret_cast<const uint4*>(hWl8 + (size_t)ip[ib + it] * 64 + gl * 16);
        addfp8x16(v, a);
    }

    // logits for this lane's classes
    bool nval = (n < N_NODES);
    float v[16];
    float mloc = -1e30f;
    if (nval && nv > 0) {
        float id = inv_deg[n];
        u16x8 r0 = *reinterpret_cast<const u16x8*>(hWr + (size_t)n * N_CLASSES + gl * 16);
        u16x8 r1 = {0, 0, 0, 0, 0, 0, 0, 0};
        if (nv > 8) r1 = *reinterpret_cast<const u16x8*>(hWr + (size_t)n * N_CLASSES + gl * 16 + 8);
#pragma unroll
        for (int i = 0; i < 16; ++i) {
            unsigned short rb = (i < 8) ? r0[i] : r1[i - 8];
            v[i] = a[i] * id + bf2f(rb);
            if (i < nv) mloc = fmaxf(mloc, v[i]);
        }
    }
    // reduce max/sum within the 4-lane group
    float m = mloc;
    m = fmaxf(m, __shfl_xor(m, 1));
    m = fmaxf(m, __shfl_xor(m, 2));
    float s = 0.f;
    if (nval) {
#pragma unroll
        for (int i = 0; i < 16; ++i)
            if (i < nv) s += expf(v[i] - m);
    }
    s += __shfl_xor(s, 1);
    s += __shfl_xor(s, 2);
    float lse = m + logf(s);
    if (nval && nv > 0) {
#pragma unroll
        for (int i0 = 0; i0 < 16; i0 += 4) {
            if (i0 < nv) {
                float4 o;
                o.x = v[i0] - lse; o.y = v[i0 + 1] - lse;
                o.z = v[i0 + 2] - lse; o.w = v[i0 + 3] - lse;
                *reinterpret_cast<float4*>(out + (size_t)n * N_CLASSES + gl * 16 + i0) = o;
            }
        }
    }
}

// ---------------- launch ----------------

extern "C" void kernel_launch(void* const* d_in, const int* in_sizes, int n_in,
                              void* d_out, int out_size, void* d_ws, size_t ws_size,
                              hipStream_t stream) {
    const float* x = (const float*)d_in[0];
    const int* ei = (const int*)d_in[1];  // int32 per harness contract
    const float* W1l = (const float*)d_in[2];
    const float* W1r = (const float*)d_in[3];
    const float* b1 = (const float*)d_in[4];
    const float* W2l = (const float*)d_in[5];
    const float* W2r = (const float*)d_in[6];
    const float* b2 = (const float*)d_in[7];
    float* out = (float*)d_out;

    char* p = (char*)d_ws;
    size_t off = 0;
    auto take = [&](size_t bytes) -> void* {
        void* r = p + off;
        off = (off + bytes + 255) & ~(size_t)255;
        return r;
    };
    int* counts = (int*)take(N_NODES * sizeof(int));
    int* row_off = (int*)take((N_NODES + 1) * sizeof(int));
    int* cursor = (int*)take(N_NODES * sizeof(int));
    float* invdeg = (float*)take(N_NODES * sizeof(float));
    int* csr_src = (int*)take(N_EDGES * sizeof(int));
    int* bsum = (int*)take((NCHUNK + 1) * sizeof(int));
    unsigned short* Wpk1 = (unsigned short*)take(256 * 256 * sizeof(unsigned short));
    unsigned short* Wpk2n = (unsigned short*)take(128 * 256 * sizeof(unsigned short));
    unsigned short* x16 = (unsigned short*)take((size_t)N_NODES * F_IN * sizeof(unsigned short));
    unsigned char* x8 = (unsigned char*)take((size_t)N_NODES * F_IN);
    unsigned char* hWl8 = (unsigned char*)take((size_t)N_NODES * 64);
    unsigned short* hWr = (unsigned short*)take((size_t)N_NODES * N_CLASSES * sizeof(unsigned short));
    // total ~= 44 MB

    zero_counts<<<(N_NODES + 255) / 256, 256, 0, stream>>>(counts);
    count_kernel<<<(N_EDGES + 255) / 256, 256, 0, stream>>>(ei + N_EDGES, counts);
    scan_partials<<<NCHUNK, 256, 0, stream>>>(counts, bsum);
    scan_apply2<<<NCHUNK, 256, 0, stream>>>(counts, bsum, row_off, cursor, invdeg);
    fill_kernel<<<(N_EDGES + 255) / 256, 256, 0, stream>>>(ei, cursor, csr_src);
    pack_w1<<<256, 256, 0, stream>>>(W1l, W1r, Wpk1);
    pack_w2n<<<128, 256, 0, stream>>>(W2l, W2r, Wpk2n);
    conv_x<<<(N_NODES * F_IN / 4 + 255) / 256, 256, 0, stream>>>(x, x16, x8);
    layer1_fused<<<NBLK, 256, 0, stream>>>(x16, x8, row_off, csr_src, invdeg, Wpk1, b1,
                                           Wpk2n, b2, hWl8, hWr);
    k2b<<<NBLK2, 256, 0, stream>>>(hWl8, hWr, row_off, csr_src, invdeg, out);
}

// Round 21
// 192.730 us; speedup vs baseline: 1.0396x; 1.0396x over previous
//
#include <hip/hip_runtime.h>
#include <math.h>

#define N_NODES 50000
#define N_EDGES 800000
#define F_IN 128
#define HIDDEN 256
#define N_CLASSES 40

#define CHUNK 256
#define NCHUNK ((N_NODES + CHUNK - 1) / CHUNK)  // 196
#define IDXCAP 1024
#define NB 32                                    // nodes per block (layer1)
#define NBLK ((N_NODES + NB - 1) / NB)           // 1563
#define NB2K 64                                  // nodes per block (k2b)
#define NBLK2 ((N_NODES + NB2K - 1) / NB2K)      // 782
#define IDXCAP2 1536

// prep kernel block ranges
#define PREP_CONV 6250                            // conv_x: 1.6M units / 256
#define PREP_W1 (PREP_CONV + 256)
#define PREP_W2 (PREP_W1 + 128)
#define PREP_ZERO (PREP_W2 + NCHUNK)

typedef __attribute__((ext_vector_type(8))) short bf16x8;
typedef __attribute__((ext_vector_type(4))) float f32x4;
typedef __attribute__((ext_vector_type(2))) float f32x2;
typedef __attribute__((ext_vector_type(8))) unsigned short u16x8;

// ---------------- bf16 helpers ----------------

__device__ __forceinline__ float bf2f(unsigned short u) {
    unsigned int t = ((unsigned int)u) << 16;
    float f;
    __builtin_memcpy(&f, &t, 4);
    return f;
}

__device__ __forceinline__ unsigned short f2bf(float f) {
    unsigned int t;
    __builtin_memcpy(&t, &f, 4);
    unsigned int r = (t + 0x7fffu + ((t >> 16) & 1u)) >> 16;  // RNE
    return (unsigned short)r;
}

// ---------------- fp8 e4m3 (OCP) helpers ----------------

__device__ __forceinline__ unsigned char f2fp8(float f) {
    unsigned int bits = __float_as_uint(f);
    unsigned int sign = (bits >> 24) & 0x80u;
    float af = fabsf(f);
    if (af >= 448.f) return (unsigned char)(sign | 0x7Eu);
    if (af < 0.015625f) {
        int m = __float2int_rn(af * 512.f);
        return (unsigned char)(sign | (unsigned int)m);
    }
    unsigned int u = bits & 0x7FFFFFFFu;
    u += 0x7FFFFu + ((u >> 20) & 1u);
    unsigned int e = (u >> 23) - 120u;
    unsigned int m = (u >> 20) & 7u;
    return (unsigned char)(sign | (e << 3) | m);
}

__device__ __forceinline__ void addfp8x8(unsigned int wx, unsigned int wy, float* a) {
#if __has_builtin(__builtin_amdgcn_cvt_pk_f32_fp8)
    f32x2 p;
    p = __builtin_amdgcn_cvt_pk_f32_fp8(wx, false); a[0] += p.x; a[1] += p.y;
    p = __builtin_amdgcn_cvt_pk_f32_fp8(wx, true);  a[2] += p.x; a[3] += p.y;
    p = __builtin_amdgcn_cvt_pk_f32_fp8(wy, false); a[4] += p.x; a[5] += p.y;
    p = __builtin_amdgcn_cvt_pk_f32_fp8(wy, true);  a[6] += p.x; a[7] += p.y;
#else
    unsigned int ww[2] = {wx, wy};
#pragma unroll
    for (int h = 0; h < 2; ++h) {
        unsigned int tlo = ww[h] & 0x00ff00ffu;
        unsigned int thi = (ww[h] >> 8) & 0x00ff00ffu;
        unsigned int rlo = ((tlo & 0x00800080u) << 8) + ((tlo & 0x007f007fu) << 4) + 0x3C003C00u;
        unsigned int rhi = ((thi & 0x00800080u) << 8) + ((thi & 0x007f007fu) << 4) + 0x3C003C00u;
        a[h * 4 + 0] += __uint_as_float(rlo << 16);
        a[h * 4 + 1] += __uint_as_float(rhi << 16);
        a[h * 4 + 2] += __uint_as_float(rlo & 0xffff0000u);
        a[h * 4 + 3] += __uint_as_float(rhi & 0xffff0000u);
    }
#endif
}

__device__ __forceinline__ void addfp8x16(uint4 w, float* a) {
    addfp8x8(w.x, w.y, a);
    addfp8x8(w.z, w.w, a + 8);
}

// ---------------- CSR build ----------------

__global__ void count_kernel(const int* __restrict__ dst, int* __restrict__ counts) {
    int e = blockIdx.x * blockDim.x + threadIdx.x;
    if (e < N_EDGES) {
        int d = dst[e];
        d = (d < 0) ? 0 : (d >= N_NODES ? N_NODES - 1 : d);
        atomicAdd(&counts[d], 1);
    }
}

__global__ __launch_bounds__(256) void scan_partials(const int* __restrict__ counts,
                                                     int* __restrict__ bsum) {
    __shared__ int red[4];
    int b = blockIdx.x;
    int i = b * CHUNK + threadIdx.x;
    int v = (i < N_NODES) ? counts[i] : 0;
    for (int off = 32; off > 0; off >>= 1) v += __shfl_down(v, off, 64);
    int wave = threadIdx.x >> 6;
    int lane = threadIdx.x & 63;
    if (lane == 0) red[wave] = v;
    __syncthreads();
    if (threadIdx.x == 0) bsum[b] = red[0] + red[1] + red[2] + red[3];
}

__global__ __launch_bounds__(256) void scan_apply2(const int* __restrict__ counts,
                                                   const int* __restrict__ bsum,
                                                   int* __restrict__ row_off,
                                                   int* __restrict__ cursor,
                                                   float* __restrict__ inv_deg) {
    __shared__ int s[256];
    __shared__ int red[4];
    int b = blockIdx.x;
    int tid = threadIdx.x;
    int r = (tid < b && tid < NCHUNK) ? bsum[tid] : 0;
    for (int off = 32; off > 0; off >>= 1) r += __shfl_down(r, off, 64);
    if ((tid & 63) == 0) red[tid >> 6] = r;
    int i = b * CHUNK + tid;
    int v = (i < N_NODES) ? counts[i] : 0;
    s[tid] = v;
    __syncthreads();
    int boff_b = red[0] + red[1] + red[2] + red[3];
    for (int off = 1; off < 256; off <<= 1) {
        int t = (tid >= off) ? s[tid - off] : 0;
        __syncthreads();
        s[tid] += t;
        __syncthreads();
    }
    if (i < N_NODES) {
        int excl = boff_b + s[tid] - v;
        row_off[i] = excl;
        cursor[i] = excl;
        inv_deg[i] = 1.0f / fmaxf((float)v, 1.0f);
        if (i == N_NODES - 1) row_off[N_NODES] = excl + v;
    }
}

__global__ void fill_kernel(const int* __restrict__ ei, int* __restrict__ cursor,
                            int* __restrict__ csr_src) {
    int e = blockIdx.x * blockDim.x + threadIdx.x;
    if (e < N_EDGES) {
        int s = ei[e];
        int d = ei[N_EDGES + e];
        s = (s < 0) ? 0 : (s >= N_NODES ? N_NODES - 1 : s);
        d = (d < 0) ? 0 : (d >= N_NODES ? N_NODES - 1 : d);
        int pos = atomicAdd(&cursor[d], 1);
        if (pos >= 0 && pos < N_EDGES) csr_src[pos] = s;
    }
}

// ---------------- prep: conv_x + pack_w1 + pack_w2n + zero_counts (fused) ----------------

__global__ __launch_bounds__(256) void prep_all(
    const float* __restrict__ x, unsigned short* __restrict__ x16,
    unsigned char* __restrict__ x8, const float* __restrict__ W1l,
    const float* __restrict__ W1r, unsigned short* __restrict__ Wpk,
    const float* __restrict__ W2l, const float* __restrict__ W2r,
    unsigned short* __restrict__ Wpk2n, int* __restrict__ counts) {
    int b = blockIdx.x;
    int tid = threadIdx.x;
    if (b < PREP_CONV) {
        int i = b * 256 + tid;
        if (i < N_NODES * F_IN / 4) {
            float4 v = reinterpret_cast<const float4*>(x)[i];
            ushort4 o;
            o.x = f2bf(v.x); o.y = f2bf(v.y); o.z = f2bf(v.z); o.w = f2bf(v.w);
            reinterpret_cast<ushort4*>(x16)[i] = o;
            uchar4 c;
            c.x = f2fp8(v.x); c.y = f2fp8(v.y); c.z = f2fp8(v.z); c.w = f2fp8(v.w);
            reinterpret_cast<uchar4*>(x8)[i] = c;
        }
    } else if (b < PREP_W1) {
        int n = b - PREP_CONV;  // 0..255
        int k = tid;
        float v = (k < F_IN) ? W1l[(size_t)k * HIDDEN + n] : W1r[(size_t)(k - F_IN) * HIDDEN + n];
        Wpk[(size_t)n * 256 + k] = f2bf(v);
    } else if (b < PREP_W2) {
        int n = b - PREP_W1;  // 0..127
        int k = tid;
        float v = 0.f;
        if (n < 64) {
            if (n < N_CLASSES) v = W2l[(size_t)k * N_CLASSES + n];
        } else {
            int m = n - 64;
            if (m < N_CLASSES) v = W2r[(size_t)k * N_CLASSES + m];
        }
        Wpk2n[(size_t)n * 256 + k] = f2bf(v);
    } else {
        int i = (b - PREP_W2) * 256 + tid;
        if (i < N_NODES) counts[i] = 0;
    }
}

// ---------------- layer1_fused: pipelined fp8 gather + MFMA1+relu + proj2 ----------
// 256 threads, 32 nodes/block; 8-lane group per node (8 rows/wave-inst).
// Gather is software-pipelined: batch N+1 loads issue BEFORE batch N dequant,
// so the compiler emits counted vmcnt and latency hides under the VALU dequant.

#define AS1_STRIDE 264

__global__ __launch_bounds__(256, 3) void layer1_fused(
    const unsigned short* __restrict__ x16, const unsigned char* __restrict__ x8,
    const int* __restrict__ row_off, const int* __restrict__ csr_src,
    const float* __restrict__ inv_deg, const unsigned short* __restrict__ Wpk,
    const float* __restrict__ b1, const unsigned short* __restrict__ Wpk2n,
    const float* __restrict__ b2, unsigned char* __restrict__ hWl8,
    unsigned short* __restrict__ hWr) {
    __shared__ __align__(16) unsigned short As[NB][AS1_STRIDE];  // A-tile, then H-tile
    __shared__ int eidx[IDXCAP];
    __shared__ int s_roff[NB + 1];
    int n0 = blockIdx.x * NB;
    int tid = threadIdx.x;
    int wave = tid >> 6;
    int lane = tid & 63;

    if (tid < NB + 1) {
        int idx = n0 + tid;
        s_roff[tid] = row_off[idx > N_NODES ? N_NODES : idx];
    }
    __syncthreads();
    int eb0 = s_roff[0];
    int eb1 = s_roff[NB];
    int cnt = eb1 - eb0;
    int staged = cnt < IDXCAP ? cnt : IDXCAP;
    for (int t = tid; t < staged; t += 256) eidx[t] = csr_src[eb0 + t];
    __syncthreads();

    // ---- phase 1: pipelined gather, 8-lane group per node ----
    int g = tid >> 3;   // node 0..31
    int gl = tid & 7;   // 16 fp8 features at gl*16
    {
        int n = n0 + g;
        int e0 = s_roff[g], e1 = s_roff[g + 1];
        int deg = e1 - e0;
        const int* ip;
        int ib;
        if (e1 - eb0 <= staged) { ip = eidx; ib = e0 - eb0; }
        else                    { ip = csr_src; ib = e0; }
        u16x8 self0 = {0, 0, 0, 0, 0, 0, 0, 0}, self1 = {0, 0, 0, 0, 0, 0, 0, 0};
        if (n < N_NODES) {
            self0 = *reinterpret_cast<const u16x8*>(x16 + (size_t)n * F_IN + gl * 16);
            self1 = *reinterpret_cast<const u16x8*>(x16 + (size_t)n * F_IN + gl * 16 + 8);
        }
        float a[16];
#pragma unroll
        for (int i = 0; i < 16; ++i) a[i] = 0.f;

        int deg8 = deg & ~7;
        if (deg8 > 0) {
            uint4 cur[8];
            {
                int ss[8];
#pragma unroll
                for (int u = 0; u < 8; ++u) ss[u] = ip[ib + u];
#pragma unroll
                for (int u = 0; u < 8; ++u)
                    cur[u] = *reinterpret_cast<const uint4*>(x8 + (size_t)ss[u] * F_IN + gl * 16);
            }
            for (int it = 8; it < deg8; it += 8) {
                int ss[8];
#pragma unroll
                for (int u = 0; u < 8; ++u) ss[u] = ip[ib + it + u];
                uint4 nxt[8];
#pragma unroll
                for (int u = 0; u < 8; ++u)
                    nxt[u] = *reinterpret_cast<const uint4*>(x8 + (size_t)ss[u] * F_IN + gl * 16);
#pragma unroll
                for (int u = 0; u < 8; ++u) addfp8x16(cur[u], a);
#pragma unroll
                for (int u = 0; u < 8; ++u) cur[u] = nxt[u];
            }
#pragma unroll
            for (int u = 0; u < 8; ++u) addfp8x16(cur[u], a);
        }
        for (int it = deg8; it < deg; ++it) {
            uint4 v = *reinterpret_cast<const uint4*>(x8 + (size_t)ip[ib + it] * F_IN + gl * 16);
            addfp8x16(v, a);
        }
        float id = (n < N_NODES) ? inv_deg[n] : 0.f;
        u16x8 m0, m1;
#pragma unroll
        for (int i = 0; i < 8; ++i) { m0[i] = f2bf(a[i] * id); m1[i] = f2bf(a[8 + i] * id); }
        *reinterpret_cast<u16x8*>(&As[g][gl * 16]) = m0;
        *reinterpret_cast<u16x8*>(&As[g][gl * 16 + 8]) = m1;
        *reinterpret_cast<u16x8*>(&As[g][F_IN + gl * 16]) = self0;
        *reinterpret_cast<u16x8*>(&As[g][F_IN + gl * 16 + 8]) = self1;
    }
    __syncthreads();

    // ---- phase 2: MFMA [mean|x]@Wpk1, 2 row-blocks (m89-verified layout) ----
    int mrow = lane & 15;
    int kg = lane >> 4;
    f32x4 acc00 = {0,0,0,0}, acc01 = {0,0,0,0}, acc02 = {0,0,0,0}, acc03 = {0,0,0,0};
    f32x4 acc10 = {0,0,0,0}, acc11 = {0,0,0,0}, acc12 = {0,0,0,0}, acc13 = {0,0,0,0};
    const unsigned short* wp = Wpk + ((size_t)(wave * 4) * 16 + mrow) * 256 + kg * 8;
#pragma unroll
    for (int ks = 0; ks < 8; ++ks) {
        bf16x8 a0 = *reinterpret_cast<const bf16x8*>(&As[mrow][ks * 32 + kg * 8]);
        bf16x8 a1 = *reinterpret_cast<const bf16x8*>(&As[16 + mrow][ks * 32 + kg * 8]);
        bf16x8 b0 = *reinterpret_cast<const bf16x8*>(wp + 0 * 16 * 256 + ks * 32);
        bf16x8 b1f = *reinterpret_cast<const bf16x8*>(wp + 1 * 16 * 256 + ks * 32);
        bf16x8 b2f = *reinterpret_cast<const bf16x8*>(wp + 2 * 16 * 256 + ks * 32);
        bf16x8 b3f = *reinterpret_cast<const bf16x8*>(wp + 3 * 16 * 256 + ks * 32);
        acc00 = __builtin_amdgcn_mfma_f32_16x16x32_bf16(a0, b0, acc00, 0, 0, 0);
        acc01 = __builtin_amdgcn_mfma_f32_16x16x32_bf16(a0, b1f, acc01, 0, 0, 0);
        acc02 = __builtin_amdgcn_mfma_f32_16x16x32_bf16(a0, b2f, acc02, 0, 0, 0);
        acc03 = __builtin_amdgcn_mfma_f32_16x16x32_bf16(a0, b3f, acc03, 0, 0, 0);
        acc10 = __builtin_amdgcn_mfma_f32_16x16x32_bf16(a1, b0, acc10, 0, 0, 0);
        acc11 = __builtin_amdgcn_mfma_f32_16x16x32_bf16(a1, b1f, acc11, 0, 0, 0);
        acc12 = __builtin_amdgcn_mfma_f32_16x16x32_bf16(a1, b2f, acc12, 0, 0, 0);
        acc13 = __builtin_amdgcn_mfma_f32_16x16x32_bf16(a1, b3f, acc13, 0, 0, 0);
    }
    __syncthreads();  // all As reads done; buffer becomes H

    // ---- phase 3: h = relu(acc + b1) -> same LDS buffer ----
    {
        f32x4 r0[4] = {acc00, acc01, acc02, acc03};
        f32x4 r1[4] = {acc10, acc11, acc12, acc13};
#pragma unroll
        for (int i = 0; i < 4; ++i) {
            int n = (wave * 4 + i) * 16 + mrow;
            float bb = b1[n];
#pragma unroll
            for (int r = 0; r < 4; ++r) {
                int row = kg * 4 + r;
                As[row][n] = f2bf(fmaxf(r0[i][r] + bb, 0.f));
                As[16 + row][n] = f2bf(fmaxf(r1[i][r] + bb, 0.f));
            }
        }
    }
    __syncthreads();

    // ---- phase 4: proj2 -- hWl8 = fp8(h@W2l) [n][64] (pad 0), hWr = h@W2r + b2 ----
    f32x4 accL0 = {0,0,0,0}, accR0 = {0,0,0,0}, accL1 = {0,0,0,0}, accR1 = {0,0,0,0};
    const unsigned short* wpL = Wpk2n + ((size_t)(wave * 16 + mrow)) * 256 + kg * 8;
    const unsigned short* wpR = Wpk2n + ((size_t)((wave + 4) * 16 + mrow)) * 256 + kg * 8;
#pragma unroll
    for (int ks = 0; ks < 8; ++ks) {
        bf16x8 a0 = *reinterpret_cast<const bf16x8*>(&As[mrow][ks * 32 + kg * 8]);
        bf16x8 a1 = *reinterpret_cast<const bf16x8*>(&As[16 + mrow][ks * 32 + kg * 8]);
        bf16x8 bL = *reinterpret_cast<const bf16x8*>(wpL + ks * 32);
        bf16x8 bR = *reinterpret_cast<const bf16x8*>(wpR + ks * 32);
        accL0 = __builtin_amdgcn_mfma_f32_16x16x32_bf16(a0, bL, accL0, 0, 0, 0);
        accR0 = __builtin_amdgcn_mfma_f32_16x16x32_bf16(a0, bR, accR0, 0, 0, 0);
        accL1 = __builtin_amdgcn_mfma_f32_16x16x32_bf16(a1, bL, accL1, 0, 0, 0);
        accR1 = __builtin_amdgcn_mfma_f32_16x16x32_bf16(a1, bR, accR1, 0, 0, 0);
    }
    int col = wave * 16 + mrow;  // 0..63
    bool cv = (col < N_CLASSES);
    float bb2 = cv ? b2[col] : 0.f;
#pragma unroll
    for (int r = 0; r < 4; ++r) {
        int row0 = n0 + kg * 4 + r;
        int row1 = row0 + 16;
        if (row0 < N_NODES) {
            hWl8[(size_t)row0 * 64 + col] = f2fp8(cv ? accL0[r] : 0.f);
            if (cv) hWr[(size_t)row0 * N_CLASSES + col] = f2bf(accR0[r] + bb2);
        }
        if (row1 < N_NODES) {
            hWl8[(size_t)row1 * 64 + col] = f2fp8(cv ? accL1[r] : 0.f);
            if (cv) hWr[(size_t)row1 * N_CLASSES + col] = f2bf(accR1[r] + bb2);
        }
    }
}

// ---------------- k2b: pipelined 4-lane-group fp8 gather + log_softmax ----------
// Group = 4 lanes x uint4 (16B) = one 64-B row => 16 rows per wave-load instruction.

__global__ __launch_bounds__(256, 3) void k2b(
    const unsigned char* __restrict__ hWl8, const unsigned short* __restrict__ hWr,
    const int* __restrict__ row_off, const int* __restrict__ csr_src,
    const float* __restrict__ inv_deg, float* __restrict__ out) {
    __shared__ int eidx[IDXCAP2];
    __shared__ int s_roff[NB2K + 1];
    int n0 = blockIdx.x * NB2K;
    int tid = threadIdx.x;

    if (tid < NB2K + 1) {
        int idx = n0 + tid;
        s_roff[tid] = row_off[idx > N_NODES ? N_NODES : idx];
    }
    __syncthreads();
    int eb0 = s_roff[0];
    int eb1 = s_roff[NB2K];
    int cnt = eb1 - eb0;
    int staged = cnt < IDXCAP2 ? cnt : IDXCAP2;
    for (int t = tid; t < staged; t += 256) eidx[t] = csr_src[eb0 + t];
    __syncthreads();

    int g = tid >> 2;   // node 0..63
    int gl = tid & 3;   // classes gl*16 .. gl*16+15
    int nv = N_CLASSES - gl * 16;
    nv = nv < 0 ? 0 : (nv > 16 ? 16 : nv);  // 16,16,8,0

    int n = n0 + g;
    int e0 = s_roff[g], e1 = s_roff[g + 1];
    int deg = e1 - e0;
    const int* ip;
    int ib;
    if (e1 - eb0 <= staged) { ip = eidx; ib = e0 - eb0; }
    else                    { ip = csr_src; ib = e0; }

    float a[16];
#pragma unroll
    for (int i = 0; i < 16; ++i) a[i] = 0.f;

    int deg8 = deg & ~7;
    if (deg8 > 0) {
        uint4 cur[8];
        {
            int ss[8];
#pragma unroll
            for (int u = 0; u < 8; ++u) ss[u] = ip[ib + u];
#pragma unroll
            for (int u = 0; u < 8; ++u)
                cur[u] = *reinterpret_cast<const uint4*>(hWl8 + (size_t)ss[u] * 64 + gl * 16);
        }
        for (int it = 8; it < deg8; it += 8) {
            int ss[8];
#pragma unroll
            for (int u = 0; u < 8; ++u) ss[u] = ip[ib + it + u];
            uint4 nxt[8];
#pragma unroll
            for (int u = 0; u < 8; ++u)
                nxt[u] = *reinterpret_cast<const uint4*>(hWl8 + (size_t)ss[u] * 64 + gl * 16);
#pragma unroll
            for (int u = 0; u < 8; ++u) addfp8x16(cur[u], a);
#pragma unroll
            for (int u = 0; u < 8; ++u) cur[u] = nxt[u];
        }
#pragma unroll
        for (int u = 0; u < 8; ++u) addfp8x16(cur[u], a);
    }
    for (int it = deg8; it < deg; ++it) {
        uint4 v = *reinterpret_cast<const uint4*>(hWl8 + (size_t)ip[ib + it] * 64 + gl * 16);
        addfp8x16(v, a);
    }

    // logits for this lane's classes
    bool nval = (n < N_NODES);
    float v[16];
    float mloc = -1e30f;
    if (nval && nv > 0) {
        float id = inv_deg[n];
        u16x8 r0 = *reinterpret_cast<const u16x8*>(hWr + (size_t)n * N_CLASSES + gl * 16);
        u16x8 r1 = {0, 0, 0, 0, 0, 0, 0, 0};
        if (nv > 8) r1 = *reinterpret_cast<const u16x8*>(hWr + (size_t)n * N_CLASSES + gl * 16 + 8);
#pragma unroll
        for (int i = 0; i < 16; ++i) {
            unsigned short rb = (i < 8) ? r0[i] : r1[i - 8];
            v[i] = a[i] * id + bf2f(rb);
            if (i < nv) mloc = fmaxf(mloc, v[i]);
        }
    }
    float m = mloc;
    m = fmaxf(m, __shfl_xor(m, 1));
    m = fmaxf(m, __shfl_xor(m, 2));
    float s = 0.f;
    if (nval) {
#pragma unroll
        for (int i = 0; i < 16; ++i)
            if (i < nv) s += expf(v[i] - m);
    }
    s += __shfl_xor(s, 1);
    s += __shfl_xor(s, 2);
    float lse = m + logf(s);
    if (nval && nv > 0) {
#pragma unroll
        for (int i0 = 0; i0 < 16; i0 += 4) {
            if (i0 < nv) {
                float4 o;
                o.x = v[i0] - lse; o.y = v[i0 + 1] - lse;
                o.z = v[i0 + 2] - lse; o.w = v[i0 + 3] - lse;
                *reinterpret_cast<float4*>(out + (size_t)n * N_CLASSES + gl * 16 + i0) = o;
            }
        }
    }
}

// ---------------- launch ----------------

extern "C" void kernel_launch(void* const* d_in, const int* in_sizes, int n_in,
                              void* d_out, int out_size, void* d_ws, size_t ws_size,
                              hipStream_t stream) {
    const float* x = (const float*)d_in[0];
    const int* ei = (const int*)d_in[1];  // int32 per harness contract
    const float* W1l = (const float*)d_in[2];
    const float* W1r = (const float*)d_in[3];
    const float* b1 = (const float*)d_in[4];
    const float* W2l = (const float*)d_in[5];
    const float* W2r = (const float*)d_in[6];
    const float* b2 = (const float*)d_in[7];
    float* out = (float*)d_out;

    char* p = (char*)d_ws;
    size_t off = 0;
    auto take = [&](size_t bytes) -> void* {
        void* r = p + off;
        off = (off + bytes + 255) & ~(size_t)255;
        return r;
    };
    int* counts = (int*)take(N_NODES * sizeof(int));
    int* row_off = (int*)take((N_NODES + 1) * sizeof(int));
    int* cursor = (int*)take(N_NODES * sizeof(int));
    float* invdeg = (float*)take(N_NODES * sizeof(float));
    int* csr_src = (int*)take(N_EDGES * sizeof(int));
    int* bsum = (int*)take((NCHUNK + 1) * sizeof(int));
    unsigned short* Wpk1 = (unsigned short*)take(256 * 256 * sizeof(unsigned short));
    unsigned short* Wpk2n = (unsigned short*)take(128 * 256 * sizeof(unsigned short));
    unsigned short* x16 = (unsigned short*)take((size_t)N_NODES * F_IN * sizeof(unsigned short));
    unsigned char* x8 = (unsigned char*)take((size_t)N_NODES * F_IN);
    unsigned char* hWl8 = (unsigned char*)take((size_t)N_NODES * 64);
    unsigned short* hWr = (unsigned short*)take((size_t)N_NODES * N_CLASSES * sizeof(unsigned short));
    // total ~= 44 MB

    prep_all<<<PREP_ZERO, 256, 0, stream>>>(x, x16, x8, W1l, W1r, Wpk1, W2l, W2r, Wpk2n, counts);
    count_kernel<<<(N_EDGES + 255) / 256, 256, 0, stream>>>(ei + N_EDGES, counts);
    scan_partials<<<NCHUNK, 256, 0, stream>>>(counts, bsum);
    scan_apply2<<<NCHUNK, 256, 0, stream>>>(counts, bsum, row_off, cursor, invdeg);
    fill_kernel<<<(N_EDGES + 255) / 256, 256, 0, stream>>>(ei, cursor, csr_src);
    layer1_fused<<<NBLK, 256, 0, stream>>>(x16, x8, row_off, csr_src, invdeg, Wpk1, b1,
                                           Wpk2n, b2, hWl8, hWr);
    k2b<<<NBLK2, 256, 0, stream>>>(hWl8, hWr, row_off, csr_src, invdeg, out);
}